// Round 5
// baseline (121.708 us; speedup 1.0000x reference)
//
#include <hip/hip_runtime.h>

// MountainCar batched rollout: B=8192 envs, 500 sequential steps of a
// 2->64->1 MLP policy + dynamics. VALU issue/latency bound; memory ~0.
//
// Round 5: (KL=16, E=2) — 65536 threads = 1024 waves (1/SIMD), each thread
// simulates TWO envs. Same total issue count as round 4's (KL=16, 2 waves),
// but the 2 independent chains/SIMD are now compiler-scheduled ILP within
// one instruction stream (deterministic stall filling), and loop overhead
// (counter/ballot/branch) is amortized over 2 envs.
// Proven pieces kept: intrinsic DPP butterfly (compiler handles the GFX9
// DPP hazard), sign-free tanh, b2 seeded into lane 0, deferred -0.1 reward
// scale, cndmask state merges.

constexpr int B = 8192;
constexpr int L = 64;
constexpr int MAX_STEPS = 500;
constexpr float GOAL_P = 0.5f;
constexpr float MIN_P  = -1.2f;
constexpr float MIN_V  = -0.07f;
constexpr float MAX_V  = 0.07f;

constexpr int KL  = 16;       // lanes per env
constexpr int UPL = L / KL;   // hidden units per lane = 4
constexpr int EPT = 2;        // envs per thread

template<int CTRL>
__device__ __forceinline__ float dpp_add(float x) {
  int y = __builtin_amdgcn_update_dpp(0, __float_as_int(x), CTRL, 0xf, 0xf, true);
  return x + __int_as_float(y);
}

__global__ __launch_bounds__(256) void mc_kernel(
    const float* __restrict__ x,  const float* __restrict__ w1,
    const float* __restrict__ b1, const float* __restrict__ w2,
    const float* __restrict__ b2, float* __restrict__ out)
{
  int tid = blockIdx.x * blockDim.x + threadIdx.x;
  int grp = tid >> 4;   // 4096 groups, 2 adjacent envs each
  int sub = tid & 15;   // lane-within-env-group

  constexpr float TS = 2.8853900817779268f;  // 2*log2(e), folded into w2/b2

  float w1a[UPL], w1b[UPL], b1r[UPL], w2r[UPL];
  const int j0 = sub * UPL;
#pragma unroll
  for (int i = 0; i < UPL; ++i) {
    w1a[i] = w1[j0 + i];          // w1[0][j]
    w1b[i] = w1[L + j0 + i];      // w1[1][j]
    b1r[i] = b1[j0 + i];
    w2r[i] = w2[j0 + i] * TS;     // w2[j][0], pre-scaled
  }
  const float b2seed = (sub == 0) ? b2[0] * TS : 0.0f;

  // Two envs per thread; all state in scalars via unrolled static indexing.
  float p[EPT], v[EPT], u[EPT], racc[EPT], r0[EPT];
#pragma unroll
  for (int k = 0; k < EPT; ++k) {
    float4 st = reinterpret_cast<const float4*>(x)[grp * EPT + k];
    p[k] = st.x; v[k] = st.y; u[k] = st.z; r0[k] = st.w;
    racc[k] = 0.0f;
  }

  for (int stp = 0; stp < MAX_STEPS; ++stp) {
    bool a0 = (p[0] <= GOAL_P);
    bool a1 = (p[1] <= GOAL_P);
    if (!__any(a0 | a1)) break;

#pragma unroll
    for (int k = 0; k < EPT; ++k) {
      bool active = (k == 0) ? a0 : a1;

      float p1 = fmaxf(p[k], MIN_P);
      float v1 = (p[k] <= MIN_P) ? 0.0f : v[k];

      // cos(3*p1): v_cos takes revolutions; independent of the MLP chain.
      float c = __builtin_amdgcn_cosf(p1 * 0.47746482927568601f);

      // Layer 1 (relu) + layer-2 partial dot, seeded with b2 on lane 0.
      float h0 = fmaxf(fmaf(v1, w1b[0], fmaf(p1, w1a[0], b1r[0])), 0.0f);
      float h1 = fmaxf(fmaf(v1, w1b[1], fmaf(p1, w1a[1], b1r[1])), 0.0f);
      float h2 = fmaxf(fmaf(v1, w1b[2], fmaf(p1, w1a[2], b1r[2])), 0.0f);
      float h3 = fmaxf(fmaf(v1, w1b[3], fmaf(p1, w1a[3], b1r[3])), 0.0f);
      float s = b2seed;
      s = fmaf(h0, w2r[0], s);
      s = fmaf(h1, w2r[1], s);
      s = fmaf(h2, w2r[2], s);
      s = fmaf(h3, w2r[3], s);

      // 16-lane butterfly; every lane ends with the full pre-scaled logit.
      s = dpp_add<0xB1>(s);     // quad_perm [1,0,3,2] : + lane^1
      s = dpp_add<0x4E>(s);     // quad_perm [2,3,0,1] : + lane^2
      s = dpp_add<0x141>(s);    // row_half_mirror    : + lane^(4..7)
      s = dpp_add<0x140>(s);    // row_mirror         : + lane^(8..15)

      // tanh, sign-free: 1 - 2/(exp2(s)+1); exact at both saturations.
      float e  = __builtin_amdgcn_exp2f(s);
      float u1 = fmaf(-2.0f, __builtin_amdgcn_rcpf(e + 1.0f), 1.0f);

      float v2 = fmaf(-0.0025f, c, fmaf(0.0015f, u1, v1));
      v2 = fminf(fmaxf(v2, MIN_V), MAX_V);
      float p2 = p1 + v2;

      if (active) {
        p[k] = p2; v[k] = v2; u[k] = u1;
        racc[k] = fmaf(u1, u1, racc[k]);
      }
    }
  }

  if (sub == 0) {
#pragma unroll
    for (int k = 0; k < EPT; ++k) {
      float rbase = fmaf(-0.1f, racc[k], r0[k]);
      float rout  = (p[k] <= GOAL_P) ? rbase : rbase + 100.0f;
      reinterpret_cast<float4*>(out)[grp * EPT + k] =
          make_float4(p[k], v[k], u[k], rout);
    }
  }
}

extern "C" void kernel_launch(void* const* d_in, const int* in_sizes, int n_in,
                              void* d_out, int out_size, void* d_ws, size_t ws_size,
                              hipStream_t stream) {
  const float* x  = (const float*)d_in[0];
  const float* w1 = (const float*)d_in[1];
  const float* b1 = (const float*)d_in[2];
  const float* w2 = (const float*)d_in[3];
  const float* b2 = (const float*)d_in[4];
  float* out = (float*)d_out;

  constexpr int threads = (B / EPT) * KL;  // 65536 -> 1024 waves -> 1/SIMD
  mc_kernel<<<threads / 256, 256, 0, stream>>>(x, w1, b1, w2, b2, out);
}

// Round 6
// 96.975 us; speedup vs baseline: 1.2550x; 1.2550x over previous
//
#include <hip/hip_runtime.h>

// MountainCar batched rollout: B=8192 envs, 500 sequential steps of a
// 2->64->1 MLP policy + dynamics. VALU issue-bound; memory ~0.
//
// Round 6 = round-4 skeleton (KL=16, 2 waves/SIMD hardware interleave —
// proven best; round 5 showed compiler ILP at 1 wave/SIMD serializes) +
// issue diet:
//  - 2-step unroll: one ballot/branch per 2 steps, halved loop phi overhead
//  - dual-chain DPP butterfly (se/so interleaved): fills the GFX9
//    VALU-write->DPP-read 2-wait-state hazard with useful work
//  - explicit v_med3 clip for v2
// Kept: intrinsic DPP (compiler owns hazards), sign-free tanh, b2 seeded
// into lane 0, deferred -0.1 reward scale, cndmask state merges.

constexpr int B = 8192;
constexpr int L = 64;
constexpr int MAX_STEPS = 500;
constexpr float GOAL_P = 0.5f;
constexpr float MIN_P  = -1.2f;
constexpr float MIN_V  = -0.07f;
constexpr float MAX_V  = 0.07f;

constexpr int KL  = 16;       // lanes per env
constexpr int UPL = L / KL;   // hidden units per lane = 4

template<int CTRL>
__device__ __forceinline__ float dpp_add(float x) {
  int y = __builtin_amdgcn_update_dpp(0, __float_as_int(x), CTRL, 0xf, 0xf, true);
  return x + __int_as_float(y);
}

__global__ __launch_bounds__(256) void mc_kernel(
    const float* __restrict__ x,  const float* __restrict__ w1,
    const float* __restrict__ b1, const float* __restrict__ w2,
    const float* __restrict__ b2, float* __restrict__ out)
{
  int tid = blockIdx.x * blockDim.x + threadIdx.x;
  int env = tid >> 4;   // env index
  int sub = tid & 15;   // lane-within-env

  constexpr float TS = 2.8853900817779268f;  // 2*log2(e), folded into w2/b2

  float w1a[UPL], w1b[UPL], b1r[UPL], w2r[UPL];
  const int j0 = sub * UPL;
#pragma unroll
  for (int i = 0; i < UPL; ++i) {
    w1a[i] = w1[j0 + i];          // w1[0][j]
    w1b[i] = w1[L + j0 + i];      // w1[1][j]
    b1r[i] = b1[j0 + i];
    w2r[i] = w2[j0 + i] * TS;     // w2[j][0], pre-scaled
  }
  // b2 seeded into lane 0's even partial chain; butterfly distributes it.
  const float b2seed = (sub == 0) ? b2[0] * TS : 0.0f;

  float4 st = reinterpret_cast<const float4*>(x)[env];
  const float r0 = st.w;
  float p = st.x, v = st.y, u = st.z;
  float racc = 0.0f;   // sum of u^2 over active steps

  // One environment step; merges state iff `active`.
  auto step = [&](bool active) {
    float p1 = fmaxf(p, MIN_P);
    float v1 = (p <= MIN_P) ? 0.0f : v;

    // cos(3*p1) in revolutions — independent trans work, issued early so
    // its latency hides under the MLP chain.
    float c = __builtin_amdgcn_cosf(p1 * 0.47746482927568601f);

    // Layer 1 (relu) + layer-2 partials in two chains (se: units 0,2 + b2
    // seed; so: units 1,3). Halves the accumulation critical path.
    float h0 = fmaxf(fmaf(v1, w1b[0], fmaf(p1, w1a[0], b1r[0])), 0.0f);
    float h1 = fmaxf(fmaf(v1, w1b[1], fmaf(p1, w1a[1], b1r[1])), 0.0f);
    float h2 = fmaxf(fmaf(v1, w1b[2], fmaf(p1, w1a[2], b1r[2])), 0.0f);
    float h3 = fmaxf(fmaf(v1, w1b[3], fmaf(p1, w1a[3], b1r[3])), 0.0f);
    float se = fmaf(h2, w2r[2], fmaf(h0, w2r[0], b2seed));
    float so = fmaf(h3, w2r[3], h1 * w2r[1]);

    // 16-lane butterfly on both chains, interleaved: each DPP op reads a
    // register written 2 instructions earlier, satisfying the GFX9
    // VALU->DPP hazard with useful work instead of s_nops.
    se = dpp_add<0xB1>(se);   so = dpp_add<0xB1>(so);    // + lane^1
    se = dpp_add<0x4E>(se);   so = dpp_add<0x4E>(so);    // + lane^2
    se = dpp_add<0x141>(se);  so = dpp_add<0x141>(so);   // + lane^(4..7)
    se = dpp_add<0x140>(se);  so = dpp_add<0x140>(so);   // + lane^(8..15)
    float s = se + so;        // full pre-scaled logit on every lane

    // tanh, sign-free: 1 - 2/(exp2(s)+1); exact at both saturations.
    float e  = __builtin_amdgcn_exp2f(s);
    float u1 = fmaf(-2.0f, __builtin_amdgcn_rcpf(e + 1.0f), 1.0f);

    float v2 = fmaf(-0.0025f, c, fmaf(0.0015f, u1, v1));
    v2 = __builtin_amdgcn_fmed3f(v2, MIN_V, MAX_V);
    float p2 = p1 + v2;

    if (active) {
      p = p2; v = v2; u = u1;
      racc = fmaf(u1, u1, racc);
    }
  };

  for (int it = 0; it < MAX_STEPS / 2; ++it) {
    bool a1 = (p <= GOAL_P);
    if (!__any(a1)) break;       // ballot shares step 1's compare
    step(a1);
    step(p <= GOAL_P);
  }

  if (sub == 0) {
    float rbase = fmaf(-0.1f, racc, r0);
    float rout  = (p <= GOAL_P) ? rbase : rbase + 100.0f;
    reinterpret_cast<float4*>(out)[env] = make_float4(p, v, u, rout);
  }
}

extern "C" void kernel_launch(void* const* d_in, const int* in_sizes, int n_in,
                              void* d_out, int out_size, void* d_ws, size_t ws_size,
                              hipStream_t stream) {
  const float* x  = (const float*)d_in[0];
  const float* w1 = (const float*)d_in[1];
  const float* b1 = (const float*)d_in[2];
  const float* w2 = (const float*)d_in[3];
  const float* b2 = (const float*)d_in[4];
  float* out = (float*)d_out;

  constexpr int threads = B * KL;  // 131072 -> 2048 waves -> 2 waves/SIMD
  mc_kernel<<<threads / 256, 256, 0, stream>>>(x, w1, b1, w2, b2, out);
}

// Round 7
// 83.591 us; speedup vs baseline: 1.4560x; 1.1601x over previous
//
#include <hip/hip_runtime.h>

// MountainCar batched rollout: B=8192 envs, 500 sequential steps of a
// 2->64->1 MLP policy + dynamics. VALU issue-bound at 2 waves/SIMD
// (R4<->R6 calibration: ~4.3 SIMD-cyc per marginal instruction).
//
// Round 7 = R4 skeleton (KL=16, 2048 waves, single 4-stage DPP butterfly)
// + WRITE-AT-CROSSING: state updates are UNCONDITIONAL (no per-step
// cndmask merges). After each update, newly-crossed envs (p > GOAL, was
// live) immediately write their final row to d_out and are removed from a
// sticky wave-uniform `live` mask. Dead envs keep computing garbage —
// finite (clips/tanh bound it), group-local (DPP stays in the 16-lane
// group), and output-irrelevant (already committed). Reference semantics
// preserved: final state = state right after the crossing update.
// Kept: intrinsic DPP (compiler owns the GFX9 DPP hazard), sign-free tanh,
// b2 seeded into lane 0, deferred -0.1 reward scale, med3 clip.

constexpr int B = 8192;
constexpr int L = 64;
constexpr int MAX_STEPS = 500;
constexpr float GOAL_P = 0.5f;
constexpr float MIN_P  = -1.2f;
constexpr float MIN_V  = -0.07f;
constexpr float MAX_V  = 0.07f;

constexpr int KL  = 16;       // lanes per env
constexpr int UPL = L / KL;   // hidden units per lane = 4

template<int CTRL>
__device__ __forceinline__ float dpp_add(float x) {
  int y = __builtin_amdgcn_update_dpp(0, __float_as_int(x), CTRL, 0xf, 0xf, true);
  return x + __int_as_float(y);
}

__global__ __launch_bounds__(256) void mc_kernel(
    const float* __restrict__ x,  const float* __restrict__ w1,
    const float* __restrict__ b1, const float* __restrict__ w2,
    const float* __restrict__ b2, float* __restrict__ out)
{
  int tid  = blockIdx.x * blockDim.x + threadIdx.x;
  int env  = tid >> 4;                 // env index
  int sub  = tid & 15;                 // lane-within-env
  int lane = threadIdx.x & 63;         // lane-within-wave

  constexpr float TS = 2.8853900817779268f;  // 2*log2(e), folded into w2/b2

  float w1a[UPL], w1b[UPL], b1r[UPL], w2r[UPL];
  const int j0 = sub * UPL;
#pragma unroll
  for (int i = 0; i < UPL; ++i) {
    w1a[i] = w1[j0 + i];          // w1[0][j]
    w1b[i] = w1[L + j0 + i];      // w1[1][j]
    b1r[i] = b1[j0 + i];
    w2r[i] = w2[j0 + i] * TS;     // w2[j][0], pre-scaled
  }
  const float b2seed = (sub == 0) ? b2[0] * TS : 0.0f;

  float4 st = reinterpret_cast<const float4*>(x)[env];
  const float r0 = st.w;
  float p = st.x, v = st.y, u = st.z;
  float racc = 0.0f;   // sum of u^2 over steps while live

  unsigned long long live = __ballot(true);   // all 64 lanes (grid exact)

  for (int stp = 0; stp < MAX_STEPS; ++stp) {
    float p1 = fmaxf(p, MIN_P);
    float v1 = (p <= MIN_P) ? 0.0f : v;

    // cos(3*p1): v_cos takes revolutions; independent of the MLP chain.
    float c = __builtin_amdgcn_cosf(p1 * 0.47746482927568601f);

    // Layer 1 (relu) + layer-2 partial dot, seeded with b2 on lane 0.
    float h0 = fmaxf(fmaf(v1, w1b[0], fmaf(p1, w1a[0], b1r[0])), 0.0f);
    float h1 = fmaxf(fmaf(v1, w1b[1], fmaf(p1, w1a[1], b1r[1])), 0.0f);
    float h2 = fmaxf(fmaf(v1, w1b[2], fmaf(p1, w1a[2], b1r[2])), 0.0f);
    float h3 = fmaxf(fmaf(v1, w1b[3], fmaf(p1, w1a[3], b1r[3])), 0.0f);
    float s = b2seed;
    s = fmaf(h0, w2r[0], s);
    s = fmaf(h1, w2r[1], s);
    s = fmaf(h2, w2r[2], s);
    s = fmaf(h3, w2r[3], s);

    // 16-lane butterfly; every lane ends with the full pre-scaled logit.
    s = dpp_add<0xB1>(s);     // quad_perm [1,0,3,2] : + lane^1
    s = dpp_add<0x4E>(s);     // quad_perm [2,3,0,1] : + lane^2
    s = dpp_add<0x141>(s);    // row_half_mirror    : + lane^(4..7)
    s = dpp_add<0x140>(s);    // row_mirror         : + lane^(8..15)

    // tanh, sign-free: 1 - 2/(exp2(s)+1); exact at both saturations.
    float e  = __builtin_amdgcn_exp2f(s);
    float u1 = fmaf(-2.0f, __builtin_amdgcn_rcpf(e + 1.0f), 1.0f);

    float v2 = fmaf(-0.0025f, c, fmaf(0.0015f, u1, v1));
    v2 = __builtin_amdgcn_fmed3f(v2, MIN_V, MAX_V);

    // Unconditional state update (no merges).
    p = p1 + v2;
    v = v2;
    u = u1;
    racc = fmaf(u1, u1, racc);

    // Crossing detection: envs whose p just exceeded GOAL write out NOW.
    unsigned long long crossed = __ballot(p > GOAL_P) & live;
    if (crossed) {                        // wave-uniform, rarely taken
      live &= ~crossed;
      if (((crossed >> lane) & 1ull) && sub == 0) {
        float rout = fmaf(-0.1f, racc, r0) + 100.0f;   // p > GOAL -> +100
        reinterpret_cast<float4*>(out)[env] = make_float4(p, v, u, rout);
      }
      if (!live) return;                  // all 4 envs in wave committed
    }
  }

  // Envs that never crossed within MAX_STEPS: p <= GOAL here, no +100.
  if (((live >> lane) & 1ull) && sub == 0) {
    float rout = fmaf(-0.1f, racc, r0);
    reinterpret_cast<float4*>(out)[env] = make_float4(p, v, u, rout);
  }
}

extern "C" void kernel_launch(void* const* d_in, const int* in_sizes, int n_in,
                              void* d_out, int out_size, void* d_ws, size_t ws_size,
                              hipStream_t stream) {
  const float* x  = (const float*)d_in[0];
  const float* w1 = (const float*)d_in[1];
  const float* b1 = (const float*)d_in[2];
  const float* w2 = (const float*)d_in[3];
  const float* b2 = (const float*)d_in[4];
  float* out = (float*)d_out;

  constexpr int threads = B * KL;  // 131072 -> 2048 waves -> 2 waves/SIMD
  mc_kernel<<<threads / 256, 256, 0, stream>>>(x, w1, b1, w2, b2, out);
}